// Round 10
// baseline (889.159 us; speedup 1.0000x reference)
//
#include <hip/hip_runtime.h>

// ---------------------------------------------------------------------------
// ACARHead forward. bf16-MFMA convs: A(weights) loaded global->VGPR
// (double-buffered, L1/L2-hot), B(activations) via LDS window; ONE barrier
// per K-step with counted vmcnt. Fused MFMA attention (QK^T -> in-register
// softmax -> PV) with GroupNorm partials in-flight.
// Activation layout: bf16 [n][p=256][c]; 14x14 payload at rows/cols 1..14.
// ---------------------------------------------------------------------------

typedef __attribute__((ext_vector_type(8))) short bhalf8;
typedef __attribute__((ext_vector_type(4))) float floatx4;

#define ACT_N 131072   // 256*512 bf16 elements per sample
#define W3SZ  2359296  // 512*512*9 (also = blocked per-tensor short count)

__device__ inline float b2f(unsigned short u) {
  union { unsigned int i; float f; } x; x.i = ((unsigned int)u) << 16; return x.f;
}
__device__ inline unsigned short f2b(float f) {
  union { float f; unsigned int i; } x; x.f = f;
  return (unsigned short)((x.i + 0x7FFFu + ((x.i >> 16) & 1u)) >> 16);
}
__device__ inline void gload_lds16(const unsigned short* g, bhalf8* l) {
  __builtin_amdgcn_global_load_lds(
      (const __attribute__((address_space(1))) unsigned int*)(const void*)g,
      (__attribute__((address_space(3))) unsigned int*)(void*)l, 16, 0, 0);
}
template <int N> __device__ inline void waitvm() {
  asm volatile("s_waitcnt vmcnt(%0)" :: "i"(N) : "memory");
}
__device__ inline void SB() { __builtin_amdgcn_sched_barrier(0); }

// ---- AdaptiveMaxPool3d(1): max over 196, write xp (f32) and out[:,0:1024] ----
__global__ void pool_max_kernel(const float* __restrict__ x, float* __restrict__ xp,
                                float* __restrict__ out) {
  int tid = threadIdx.x;
  int wid = blockIdx.x * 4 + (tid >> 6);   // n*1024 + c
  int lane = tid & 63;
  int n = wid >> 10, c = wid & 1023;
  const float* p = x + (size_t)wid * 196;
  float v = -3.4e38f;
  v = fmaxf(v, p[lane]);
  v = fmaxf(v, p[lane + 64]);
  v = fmaxf(v, p[lane + 128]);
  if (lane < 4) v = fmaxf(v, p[lane + 192]);
#pragma unroll
  for (int off = 32; off >= 1; off >>= 1) v = fmaxf(v, __shfl_xor(v, off));
  if (lane == 0) { xp[wid] = v; out[(size_t)n * 1536 + c] = v; }
}

// ---- bias1[n][o] = sum_{c<1024} w1[o][1024+c] * xp[n][c]  (f32) ----
__global__ void bias1_kernel(const float* __restrict__ w1, const float* __restrict__ xp,
                             float* __restrict__ bias1) {
  int tid = threadIdx.x;
  int wid = blockIdx.x * 4 + (tid >> 6);   // n*512 + o
  int lane = tid & 63;
  int n = wid >> 9, o = wid & 511;
  const float* wr = w1 + (size_t)o * 2048 + 1024;
  const float* xr = xp + (size_t)n * 1024;
  float s = 0.f;
#pragma unroll
  for (int r = 0; r < 16; r++) { int c = lane + r * 64; s += wr[c] * xr[c]; }
#pragma unroll
  for (int off = 32; off >= 1; off >>= 1) s += __shfl_xor(s, off);
  if (lane == 0) bias1[wid] = s;
}

// ---- 3x3 weight prep -> tap-grouped blocked layout ----
// Wg2[tensor][ot(8)][ks(16)][slot u(2304)][8 bf16]:
//   u = g*768 + (dh*4+kg)*64 + o ; data = w[o0+o][ks*32+kg*8+j][dh*3+g]
__global__ __launch_bounds__(256) void wprep3_kernel(
    const float* __restrict__ w2, const float* __restrict__ wq,
    const float* __restrict__ wk, const float* __restrict__ wv,
    const float* __restrict__ wm, unsigned short* __restrict__ Wg2) {
  int ks = blockIdx.x, ot = blockIdx.y, tid = blockIdx.z;
  int t = threadIdx.x;
  const float* src;
  if (tid == 0) src = w2;
  else {
    int d = (tid - 1) >> 2, r = (tid - 1) & 3;
    src = (r == 0 ? wq : r == 1 ? wk : r == 2 ? wv : wm) + (size_t)d * W3SZ;
  }
  __shared__ unsigned short S[64 * 288];
  const float* sb = src + (size_t)ot * 64 * 4608 + (size_t)ks * 288;
  for (int j = 0; j < 72; j++) {
    int flat = j * 256 + t;          // < 18432
    int o = flat / 288, ci = flat % 288;
    S[flat] = f2b(sb[(size_t)o * 4608 + ci]);
  }
  __syncthreads();
  unsigned short* dst = Wg2 + (((size_t)(tid * 8 + ot) * 16 + ks) * 2304) * 8;
#pragma unroll
  for (int s = 0; s < 9; s++) {
    int u = t + s * 256;
    int g = u / 768, rem = u % 768;
    int rl = rem >> 6, o = rem & 63;
    int dh = rl >> 2, kg = rl & 3;
    int t9src = dh * 3 + g;
    bhalf8 v;
#pragma unroll
    for (int j = 0; j < 8; j++) v[j] = (short)S[o * 288 + (kg * 8 + j) * 9 + t9src];
    *(bhalf8*)(dst + (size_t)u * 8) = v;
  }
}

// ---- conv1 weight prep -> blocked: W1g[ot(8)][ks(32)][slot(256)][8] ----
__global__ void w1prep_kernel(const float* __restrict__ w1, unsigned short* __restrict__ W1g) {
  int ks = blockIdx.x, ot = blockIdx.y, t = threadIdx.x;
  int kg = t >> 6, o = t & 63;
  const float* s = w1 + (size_t)(ot * 64 + o) * 2048 + ks * 32 + kg * 8;
  bhalf8 v;
#pragma unroll
  for (int j = 0; j < 8; j++) v[j] = (short)f2b(s[j]);
  *(bhalf8*)(W1g + (((size_t)ot * 32 + ks) * 256 + t) * 8) = v;
}

// ---- feat transpose: feat[img][c][p] f32 -> featT[img][p][c] bf16 ----
__global__ __launch_bounds__(256) void ftprep_kernel(
    const float* __restrict__ feat, unsigned short* __restrict__ featT) {
  int img = blockIdx.z, c0 = blockIdx.y * 64, p0 = blockIdx.x * 64;
  int t = threadIdx.x;
  int a = t >> 6, b = t & 63;
  __shared__ float S[64][65];
#pragma unroll
  for (int j = 0; j < 16; j++) {
    int r = a * 16 + j;
    S[r][b] = feat[((size_t)img * 1024 + c0 + r) * 256 + p0 + b];
  }
  __syncthreads();
#pragma unroll
  for (int j = 0; j < 16; j++) {
    int pl = a * 16 + j;
    featT[((size_t)img * 256 + p0 + pl) * 1024 + c0 + b] = f2b(S[b][pl]);
  }
}

// ---------------------------------------------------------------------------
// Unified MFMA conv: A from global (reg double-buffer, issued 1 phase ahead),
// B from LDS tap-window; 1 barrier per K-step, counted vmcnt.
// Block tile 64o x (256/PSPLIT)p; per-wave 64o x (NREP*16)p.
// ---------------------------------------------------------------------------
template <int TAPS, int KTOT, int WAVES, int NREP, int PSPLIT,
          bool RELU, bool ADD, bool BIAS, bool VALID>
__global__ __launch_bounds__(WAVES * 64) void conv_mfma_kernel(
    const unsigned short* __restrict__ Xg, const int* __restrict__ rois,
    const unsigned short* __restrict__ Wg, const float* __restrict__ bias,
    unsigned short* __restrict__ Out) {
  constexpr int THREADS = WAVES * 64;
  constexpr int NK = KTOT / 32;
  constexpr int LX = 1024 / THREADS;
  static_assert(PSPLIT * WAVES * NREP * 16 == 256, "p coverage");
  static_assert(1024 % THREADS == 0, "stage div");
  __shared__ bhalf8 Xs[2][1024];

  int n = blockIdx.y;
  int ot = blockIdx.x / PSPLIT;
  int pq = blockIdx.x % PSPLIT;
  int t = threadIdx.x;
  int wv = t >> 6, l = t & 63, l15 = l & 15, l4 = l >> 4;
  int pbase = (pq * WAVES + wv) * (NREP * 16);
  const unsigned short* xb =
      Xg + (rois ? (size_t)rois[n * 5] * 256 * KTOT : (size_t)n * 256 * KTOT);
  floatx4 acc[4][NREP] = {};

  auto stageX = [&](int xbuf, int ks) {
#pragma unroll
    for (int i = 0; i < LX; i++) {
      int base = i * THREADS + wv * 64;
      int u = base + l;
      int p = u & 255, kg = u >> 8;
      gload_lds16(xb + (size_t)p * KTOT + ks * 32 + kg * 8, &Xs[xbuf][base]);
    }
  };

  if constexpr (TAPS == 9) {
    const unsigned short* wB = Wg + (size_t)ot * NK * 2304 * 8;
    bhalf8 A0[12], A1[12];
    auto issueA = [&](bhalf8 (&dst)[12], int ks, int g) {
      const unsigned short* wp = wB + ((size_t)ks * 2304 + g * 768 + l4 * 64 + l15) * 8;
#pragma unroll
      for (int dh = 0; dh < 3; dh++)
#pragma unroll
        for (int of = 0; of < 4; of++)
          dst[dh * 4 + of] = *(const bhalf8*)(wp + (size_t)(dh * 256 + of * 16) * 8);
    };
    auto computeG = [&](const bhalf8* X, const bhalf8 (&A)[12], int g) {
      bhalf8 BW[NREP + 2];
#pragma unroll
      for (int w10 = 0; w10 < NREP + 2; w10++)
        BW[w10] = X[l4 * 256 + ((pbase + w10 * 16 + l15 + g) & 255)];
      __builtin_amdgcn_s_setprio(1);
#pragma unroll
      for (int dh = 0; dh < 3; dh++)
#pragma unroll
        for (int of = 0; of < 4; of++)
#pragma unroll
          for (int pf = 0; pf < NREP; pf++)
            acc[of][pf] = __builtin_amdgcn_mfma_f32_16x16x32_bf16(
                A[dh * 4 + of], BW[pf + dh], acc[of][pf], 0, 0, 0);
      __builtin_amdgcn_s_setprio(0);
    };

    // prologue: X(0) then A(0,g0); X drained by waitvm<12> (12 newer = A)
    stageX(0, 0);
    issueA(A0, 0, 0); SB();
    waitvm<12>();
    __builtin_amdgcn_s_barrier(); SB();

    for (int ks = 0; ks < NK - 2; ks += 2) {
      const bhalf8* Xe = Xs[ks & 1];
      // even K-step ks (g0 operands in A0)
      issueA(A1, ks, 1); SB();
      waitvm<12>(); computeG(Xe, A0, 0); SB();
      issueA(A0, ks, 2); stageX((ks + 1) & 1, ks + 1); SB();
      waitvm<16>(); computeG(Xe, A1, 1); SB();
      issueA(A1, ks + 1, 0); SB();
      waitvm<16>(); computeG(Xe, A0, 2); SB();
      waitvm<12>();                       // drains X(ks+1); A(ks+1,g0) stays
      __builtin_amdgcn_s_barrier(); SB();
      // odd K-step ks+1 (g0 operands in A1)
      const bhalf8* Xo = Xs[(ks + 1) & 1];
      issueA(A0, ks + 1, 1); SB();
      waitvm<12>(); computeG(Xo, A1, 0); SB();
      issueA(A1, ks + 1, 2); stageX(ks & 1, ks + 2); SB();
      waitvm<16>(); computeG(Xo, A0, 1); SB();
      issueA(A0, ks + 2, 0); SB();
      waitvm<16>(); computeG(Xo, A1, 2); SB();
      waitvm<12>();
      __builtin_amdgcn_s_barrier(); SB();
    }
    {
      const int ks = NK - 2;              // even
      const bhalf8* Xe = Xs[ks & 1];
      issueA(A1, ks, 1); SB();
      waitvm<12>(); computeG(Xe, A0, 0); SB();
      issueA(A0, ks, 2); stageX((ks + 1) & 1, ks + 1); SB();
      waitvm<16>(); computeG(Xe, A1, 1); SB();
      issueA(A1, ks + 1, 0); SB();
      waitvm<16>(); computeG(Xe, A0, 2); SB();
      waitvm<12>();
      __builtin_amdgcn_s_barrier(); SB();
      // tail K-step NK-1 (odd)
      const bhalf8* Xo = Xs[(ks + 1) & 1];
      issueA(A0, ks + 1, 1); SB();
      waitvm<12>(); computeG(Xo, A1, 0); SB();
      issueA(A1, ks + 1, 2); SB();
      waitvm<12>(); computeG(Xo, A0, 1); SB();
      waitvm<0>(); computeG(Xo, A1, 2); SB();
    }
  } else {
    // TAPS == 1 (conv1)
    const unsigned short* wB = Wg + (size_t)ot * NK * 256 * 8;
    bhalf8 A0[4], A1[4];
    auto issueA1 = [&](bhalf8 (&dst)[4], int ks) {
      const unsigned short* wp = wB + ((size_t)ks * 256 + l4 * 64 + l15) * 8;
#pragma unroll
      for (int of = 0; of < 4; of++)
        dst[of] = *(const bhalf8*)(wp + (size_t)(of * 16) * 8);
    };
    auto compute1 = [&](const bhalf8* X, const bhalf8 (&A)[4]) {
      bhalf8 B[NREP];
#pragma unroll
      for (int pf = 0; pf < NREP; pf++)
        B[pf] = X[l4 * 256 + ((pbase + pf * 16 + l15) & 255)];
      __builtin_amdgcn_s_setprio(1);
#pragma unroll
      for (int of = 0; of < 4; of++)
#pragma unroll
        for (int pf = 0; pf < NREP; pf++)
          acc[of][pf] = __builtin_amdgcn_mfma_f32_16x16x32_bf16(
              A[of], B[pf], acc[of][pf], 0, 0, 0);
      __builtin_amdgcn_s_setprio(0);
    };

    stageX(0, 0);
    issueA1(A0, 0); SB();
    waitvm<4>();                           // X(0) drained (4 newer = A(0))
    __builtin_amdgcn_s_barrier(); SB();
    for (int ks = 0; ks < NK - 2; ks += 2) {
      // even
      stageX((ks + 1) & 1, ks + 1); issueA1(A1, ks + 1); SB();
      waitvm<8>(); compute1(Xs[ks & 1], A0); SB();
      waitvm<4>(); __builtin_amdgcn_s_barrier(); SB();
      // odd
      stageX(ks & 1, ks + 2); issueA1(A0, ks + 2); SB();
      waitvm<8>(); compute1(Xs[(ks + 1) & 1], A1); SB();
      waitvm<4>(); __builtin_amdgcn_s_barrier(); SB();
    }
    {
      const int ks = NK - 2;
      stageX((ks + 1) & 1, ks + 1); issueA1(A1, ks + 1); SB();
      waitvm<8>(); compute1(Xs[ks & 1], A0); SB();
      waitvm<4>(); __builtin_amdgcn_s_barrier(); SB();
      waitvm<0>(); compute1(Xs[(ks + 1) & 1], A1); SB();
    }
  }

#pragma unroll
  for (int of = 0; of < 4; of++) {
    int og = ot * 64 + of * 16 + l4 * 4;
    int tensor = og >> 9, ol = og & 511;
#pragma unroll
    for (int pf = 0; pf < NREP; pf++) {
      int p = pbase + pf * 16 + l15;
      int po = p;
      if (VALID) {
        int h = p >> 4, w = p & 15;
        if (h >= 14 || w >= 14) continue;
        po = (h + 1) * 16 + (w + 1);
      }
      unsigned short* dp = Out + (((size_t)tensor * 32 + n) * 256 + po) * 512 + ol;
      float vv[4];
#pragma unroll
      for (int r2 = 0; r2 < 4; r2++) vv[r2] = acc[of][pf][r2];
      if (BIAS) {
#pragma unroll
        for (int r2 = 0; r2 < 4; r2++) vv[r2] += bias[(size_t)n * 512 + ol + r2];
      }
      if (ADD) {
        ushort4 old = *(const ushort4*)dp;
        vv[0] += b2f(old.x); vv[1] += b2f(old.y); vv[2] += b2f(old.z); vv[3] += b2f(old.w);
      }
      if (RELU) {
#pragma unroll
        for (int r2 = 0; r2 < 4; r2++) vv[r2] = fmaxf(vv[r2], 0.f);
      }
      ushort4 st = { f2b(vv[0]), f2b(vv[1]), f2b(vv[2]), f2b(vv[3]) };
      *(ushort4*)dp = st;
    }
  }
}

// ---- V transpose: bufv[kn][pp][c] -> vt[ppc][c][kn]  (interior pp only) ----
__global__ __launch_bounds__(256) void vtrans_kernel(
    const unsigned short* __restrict__ v, unsigned short* __restrict__ vt) {
  int ppc = blockIdx.x;                       // 0..195
  int pp = (ppc / 14 + 1) * 16 + ppc % 14 + 1;
  int t = threadIdx.x;
  __shared__ unsigned short S[32 * 512];
#pragma unroll
  for (int i = 0; i < 8; i++) {
    int u = i * 256 + t;
    int kn = u >> 6, c8 = (u & 63) * 8;
    *(bhalf8*)&S[kn * 512 + c8] = *(const bhalf8*)(v + ((size_t)kn * 256 + pp) * 512 + c8);
  }
  __syncthreads();
#pragma unroll
  for (int half = 0; half < 2; half++) {
    int c = half * 256 + t;
    unsigned int col[16];
#pragma unroll
    for (int j = 0; j < 16; j++)
      col[j] = (unsigned int)S[(2 * j) * 512 + c] |
               ((unsigned int)S[(2 * j + 1) * 512 + c] << 16);
    unsigned short* dst = vt + ((size_t)ppc * 512 + c) * 32;
#pragma unroll
    for (int j = 0; j < 4; j++) {
      uint4 P = { col[j * 4], col[j * 4 + 1], col[j * 4 + 2], col[j * 4 + 3] };
      *(uint4*)(dst + j * 8) = P;
    }
  }
}

// ---------------------------------------------------------------------------
// Fused attention per pixel: QK^T (MFMA) -> in-register softmax -> PV (MFMA,
// C^T form via pre-transposed V) -> store vf + GroupNorm partials.
// ---------------------------------------------------------------------------
__global__ __launch_bounds__(64) void attfused_kernel(
    const unsigned short* __restrict__ q, const unsigned short* __restrict__ k,
    const unsigned short* __restrict__ vt, unsigned short* __restrict__ out,
    float* __restrict__ gnpart) {
  int pp = blockIdx.x;
  int h = pp >> 4, w = pp & 15;
  int l = threadIdx.x, l15 = l & 15, l4 = l >> 4;
  if (h < 1 || h > 14 || w < 1 || w > 14) {
    uint4 z = {0u, 0u, 0u, 0u};
#pragma unroll
    for (int qn = 0; qn < 32; qn++)
      *(uint4*)(out + ((size_t)qn * 256 + pp) * 512 + l * 8) = z;
    return;
  }
  int ppc = (h - 1) * 14 + (w - 1);

  // ---- QK^T: C[kn32][qn32], K=512 ----
  floatx4 sc[2][2] = {};
#pragma unroll
  for (int kb = 0; kb < 16; kb++) {
    bhalf8 A[2], B[2];
#pragma unroll
    for (int of = 0; of < 2; of++)
      A[of] = *(const bhalf8*)(k + ((size_t)(of * 16 + l15) * 256 + pp) * 512 + kb * 32 + l4 * 8);
#pragma unroll
    for (int pf = 0; pf < 2; pf++)
      B[pf] = *(const bhalf8*)(q + ((size_t)(pf * 16 + l15) * 256 + pp) * 512 + kb * 32 + l4 * 8);
#pragma unroll
    for (int of = 0; of < 2; of++)
#pragma unroll
      for (int pf = 0; pf < 2; pf++)
        sc[of][pf] = __builtin_amdgcn_mfma_f32_16x16x32_bf16(A[of], B[pf], sc[of][pf], 0, 0, 0);
  }

  // ---- softmax over kn (rows), per qn column; P -> LDS bf16 normalized ----
  __shared__ unsigned short p_lds[32 * 32];
  const float scale = 0.044194173824159216f;
#pragma unroll
  for (int pf = 0; pf < 2; pf++) {
    float v8[8];
    float m = -3.4e38f;
#pragma unroll
    for (int of = 0; of < 2; of++)
#pragma unroll
      for (int r = 0; r < 4; r++) {
        float x = sc[of][pf][r] * scale;
        v8[of * 4 + r] = x;
        m = fmaxf(m, x);
      }
    m = fmaxf(m, __shfl_xor(m, 16));
    m = fmaxf(m, __shfl_xor(m, 32));
    float s = 0.f;
#pragma unroll
    for (int i = 0; i < 8; i++) { v8[i] = __expf(v8[i] - m); s += v8[i]; }
    s += __shfl_xor(s, 16);
    s += __shfl_xor(s, 32);
    float inv = 1.f / s;
#pragma unroll
    for (int of = 0; of < 2; of++) {
      ushort4 pk = { f2b(v8[of * 4 + 0] * inv), f2b(v8[of * 4 + 1] * inv),
                     f2b(v8[of * 4 + 2] * inv), f2b(v8[of * 4 + 3] * inv) };
      *(ushort4*)&p_lds[(pf * 16 + l15) * 32 + of * 16 + l4 * 4] = pk;
    }
  }

  // ---- PV as C^T: C[c512][qn32] = VT[c][kn] @ P[qn][kn]^T, K=32 ----
  bhalf8 PB[2];
#pragma unroll
  for (int qf = 0; qf < 2; qf++)
    PB[qf] = *(const bhalf8*)&p_lds[(qf * 16 + l15) * 32 + l4 * 8];
  float gs[2] = {0.f, 0.f}, gss[2] = {0.f, 0.f};
  const unsigned short* vtb = vt + (size_t)ppc * 512 * 32;
#pragma unroll
  for (int chunk = 0; chunk < 4; chunk++) {
    bhalf8 VA[8];
#pragma unroll
    for (int co = 0; co < 8; co++)
      VA[co] = *(const bhalf8*)(vtb + (size_t)(chunk * 128 + co * 16 + l15) * 32 + l4 * 8);
#pragma unroll
    for (int co = 0; co < 8; co++)
#pragma unroll
      for (int qf = 0; qf < 2; qf++) {
        floatx4 pa = __builtin_amdgcn_mfma_f32_16x16x32_bf16(
            VA[co], PB[qf], (floatx4){0.f, 0.f, 0.f, 0.f}, 0, 0, 0);
        float x0 = pa[0], x1 = pa[1], x2 = pa[2], x3 = pa[3];
        gs[qf] += x0 + x1 + x2 + x3;
        gss[qf] += x0 * x0 + x1 * x1 + x2 * x2 + x3 * x3;
        ushort4 st = { f2b(x0), f2b(x1), f2b(x2), f2b(x3) };
        int qn = qf * 16 + l15;
        int c = chunk * 128 + co * 16 + l4 * 4;
        *(ushort4*)(out + ((size_t)qn * 256 + pp) * 512 + c) = st;
      }
  }
#pragma unroll
  for (int qf = 0; qf < 2; qf++) {
    gs[qf] += __shfl_xor(gs[qf], 16);  gs[qf] += __shfl_xor(gs[qf], 32);
    gss[qf] += __shfl_xor(gss[qf], 16); gss[qf] += __shfl_xor(gss[qf], 32);
  }
  if (l4 == 0) {
#pragma unroll
    for (int qf = 0; qf < 2; qf++) {
      int qn = qf * 16 + l15;
      gnpart[((size_t)ppc * 32 + qn) * 2]     = gs[qf];
      gnpart[((size_t)ppc * 32 + qn) * 2 + 1] = gss[qf];
    }
  }
}

// ---- GroupNorm: reduce partials + apply affine + relu (interior only) ----
__global__ __launch_bounds__(256) void gnapply3_kernel(
    unsigned short* __restrict__ x, const float* __restrict__ gnpart,
    const float* __restrict__ gamma, const float* __restrict__ beta) {
  int n = blockIdx.y, half = blockIdx.x, t = threadIdx.x;
  float s = 0.f, ss = 0.f;
  if (t < 196) {
    s  = gnpart[((size_t)t * 32 + n) * 2];
    ss = gnpart[((size_t)t * 32 + n) * 2 + 1];
  }
#pragma unroll
  for (int off = 32; off >= 1; off >>= 1) { s += __shfl_xor(s, off); ss += __shfl_xor(ss, off); }
  __shared__ float sm[8];
  int wv = t >> 6, ln = t & 63;
  if (ln == 0) { sm[wv] = s; sm[4 + wv] = ss; }
  __syncthreads();
  float S = sm[0] + sm[1] + sm[2] + sm[3];
  float SS = sm[4] + sm[5] + sm[6] + sm[7];
  const float M = 512.f * 196.f;
  float mu = S / M;
  float var = SS / M - mu * mu;
  float inv = rsqrtf(var + 1e-5f);
  int c2 = t * 2;
  unsigned short* xb = x + (size_t)n * ACT_N;
  float g0 = gamma[c2], g1 = gamma[c2 + 1];
  float be0 = beta[c2], be1 = beta[c2 + 1];
  for (int i = 0; i < 98; i++) {
    int ppc = half * 98 + i;
    int pp = (ppc / 14 + 1) * 16 + ppc % 14 + 1;
    unsigned int vv = *(unsigned int*)(xb + pp * 512 + c2);
    float a = (b2f((unsigned short)vv) - mu) * inv * g0 + be0;
    float b = (b2f((unsigned short)(vv >> 16)) - mu) * inv * g1 + be1;
    a = fmaxf(a, 0.f); b = fmaxf(b, 0.f);
    *(unsigned int*)(xb + pp * 512 + c2) =
        (unsigned int)f2b(a) | ((unsigned int)f2b(b) << 16);
  }
}

// ---- final: mean over interior 196 -> out[n][1024+c] (f32) ----
__global__ void fmean2_kernel(const unsigned short* __restrict__ x, float* __restrict__ out) {
  int n = blockIdx.x, t = threadIdx.x;
  const unsigned short* xb = x + (size_t)n * ACT_N;
  float s0 = 0.f, s1 = 0.f;
  for (int i = 0; i < 196; i++) {
    int pp = (i / 14 + 1) * 16 + (i % 14) + 1;
    unsigned int vv = *(const unsigned int*)(xb + pp * 512 + t * 2);
    s0 += b2f((unsigned short)vv);
    s1 += b2f((unsigned short)(vv >> 16));
  }
  out[(size_t)n * 1536 + 1024 + t * 2]     = s0 * (1.f / 196.f);
  out[(size_t)n * 1536 + 1024 + t * 2 + 1] = s1 * (1.f / 196.f);
}

extern "C" void kernel_launch(void* const* d_in, const int* in_sizes, int n_in,
                              void* d_out, int out_size, void* d_ws, size_t ws_size,
                              hipStream_t stream) {
  const float* x     = (const float*)d_in[0];
  const float* feat  = (const float*)d_in[1];
  const int*   rois  = (const int*)d_in[2];
  const float* w1    = (const float*)d_in[3];
  const float* w2    = (const float*)d_in[4];
  const float* wq    = (const float*)d_in[5];
  const float* wk    = (const float*)d_in[6];
  const float* wv    = (const float*)d_in[7];
  const float* wm    = (const float*)d_in[8];
  const float* gamma = (const float*)d_in[9];
  const float* beta  = (const float*)d_in[10];
  float* out = (float*)d_out;

  // ---- workspace layout ----
  // vt (6.42 MB) ALIASES [xp..W1g]: those are only used before the d-loop.
  float* wsf   = (float*)d_ws;
  float* xp    = wsf;                // 32768 f32
  float* bias1 = xp + 32768;         // 16384 f32
  float* stats = bias1 + 16384;      // 64 f32 (layout keep)
  float* attf  = stats + 64;         // 262144 f32 (layout keep)
  unsigned short* ub    = (unsigned short*)(attf + 262144);
  unsigned short* featT = ub;                    // 2097152 shorts
  unsigned short* W1g   = featT + 2097152;       // 524288 shorts
  unsigned short* Wg2   = W1g + 524288;          // 13*W3SZ shorts
  unsigned short* bufq  = Wg2 + 30670848;        // q/k/v contiguous
  unsigned short* bufk  = bufq + 4194304;
  unsigned short* bufv  = bufk + 4194304;
  unsigned short* bufx  = bufv + 4194304;
  unsigned short* vt    = (unsigned short*)d_ws; // 196*512*32 shorts
  float* gnpart = (float*)(bufx + 4194304);      // 196*32*2 f32

  // bufx border rows must be zero (only interior ever written by convs)
  hipMemsetAsync(bufx, 0, (size_t)4194304 * 2, stream);

  pool_max_kernel<<<8192, 256, 0, stream>>>(x, xp, out);
  bias1_kernel<<<4096, 256, 0, stream>>>(w1, xp, bias1);
  wprep3_kernel<<<dim3(16, 8, 13), 256, 0, stream>>>(w2, wq, wk, wv, wm, Wg2);
  w1prep_kernel<<<dim3(32, 8), 256, 0, stream>>>(w1, W1g);
  ftprep_kernel<<<dim3(4, 16, 8), 256, 0, stream>>>(feat, featT);

  // conv1: 1x1, K=1024, +bias1, relu, full 16x16 output -> bufq
  conv_mfma_kernel<1, 1024, 4, 4, 1, true, false, true, false>
      <<<dim3(8, 32), 256, 0, stream>>>(featT, rois, W1g, bias1, bufq);
  // conv2: valid 3x3 -> padded interior of bufx, relu
  conv_mfma_kernel<9, 512, 4, 4, 1, true, false, false, true>
      <<<dim3(8, 32), 256, 0, stream>>>(bufq, nullptr, Wg2, nullptr, bufx);

  for (int d = 0; d < 3; d++) {
    // q,k,v batched conv
    conv_mfma_kernel<9, 512, 4, 4, 1, false, false, false, true>
        <<<dim3(24, 32), 256, 0, stream>>>(bufx, nullptr,
            Wg2 + (size_t)(1 + 4 * d) * W3SZ, nullptr, bufq);
    vtrans_kernel<<<196, 256, 0, stream>>>(bufv, vt);
    attfused_kernel<<<256, 64, 0, stream>>>(bufq, bufk, vt, bufq, gnpart);
    gnapply3_kernel<<<dim3(2, 32), 256, 0, stream>>>(bufq, gnpart,
        gamma + d * 512, beta + d * 512);
    // wm conv + residual add into bufx
    conv_mfma_kernel<9, 512, 4, 4, 1, false, true, false, true>
        <<<dim3(8, 32), 256, 0, stream>>>(bufq, nullptr,
            Wg2 + (size_t)(4 + 4 * d) * W3SZ, nullptr, bufx);
  }

  fmean2_kernel<<<32, 256, 0, stream>>>(bufx, out);
}

// Round 11
// 766.698 us; speedup vs baseline: 1.1597x; 1.1597x over previous
//
#include <hip/hip_runtime.h>

// ---------------------------------------------------------------------------
// ACARHead forward. bf16-MFMA convs (depth-2 counted-vmcnt pipeline + setprio,
// W staged via global_load_lds into 3 rotating LDS buffers) + fused MFMA
// attention (QK^T -> in-register softmax -> PV) with GroupNorm partials.
// Grid order x=n, y=ot so same-W blocks are XCD-L2-adjacent (T1 mechanism).
// Activation layout: bf16 [n][p=256][c]; 14x14 payload at rows/cols 1..14.
// ---------------------------------------------------------------------------

typedef __attribute__((ext_vector_type(8))) short bhalf8;
typedef __attribute__((ext_vector_type(4))) float floatx4;

#define ACT_N 131072   // 256*512 bf16 elements per sample
#define W3SZ  2359296  // 512*512*9 (also = blocked per-tensor short count)

__device__ inline float b2f(unsigned short u) {
  union { unsigned int i; float f; } x; x.i = ((unsigned int)u) << 16; return x.f;
}
__device__ inline unsigned short f2b(float f) {
  union { float f; unsigned int i; } x; x.f = f;
  return (unsigned short)((x.i + 0x7FFFu + ((x.i >> 16) & 1u)) >> 16);
}
__device__ inline void gload_lds16(const unsigned short* g, bhalf8* l) {
  __builtin_amdgcn_global_load_lds(
      (const __attribute__((address_space(1))) unsigned int*)(const void*)g,
      (__attribute__((address_space(3))) unsigned int*)(void*)l, 16, 0, 0);
}
template <int N> __device__ inline void waitvm() {
  asm volatile("s_waitcnt vmcnt(%0)" :: "i"(N) : "memory");
}
__device__ inline void phase_barrier_pre() {
  __builtin_amdgcn_sched_barrier(0);
  __builtin_amdgcn_s_barrier();
  __builtin_amdgcn_sched_barrier(0);
}
__device__ inline void phase_barrier_post() {
  __builtin_amdgcn_sched_barrier(0);
  __builtin_amdgcn_s_barrier();
  __builtin_amdgcn_sched_barrier(0);
}

// ---- AdaptiveMaxPool3d(1): max over 196, write xp (f32) and out[:,0:1024] ----
__global__ void pool_max_kernel(const float* __restrict__ x, float* __restrict__ xp,
                                float* __restrict__ out) {
  int tid = threadIdx.x;
  int wid = blockIdx.x * 4 + (tid >> 6);   // n*1024 + c
  int lane = tid & 63;
  int n = wid >> 10, c = wid & 1023;
  const float* p = x + (size_t)wid * 196;
  float v = -3.4e38f;
  v = fmaxf(v, p[lane]);
  v = fmaxf(v, p[lane + 64]);
  v = fmaxf(v, p[lane + 128]);
  if (lane < 4) v = fmaxf(v, p[lane + 192]);
#pragma unroll
  for (int off = 32; off >= 1; off >>= 1) v = fmaxf(v, __shfl_xor(v, off));
  if (lane == 0) { xp[wid] = v; out[(size_t)n * 1536 + c] = v; }
}

// ---- bias1[n][o] = sum_{c<1024} w1[o][1024+c] * xp[n][c]  (f32) ----
__global__ void bias1_kernel(const float* __restrict__ w1, const float* __restrict__ xp,
                             float* __restrict__ bias1) {
  int tid = threadIdx.x;
  int wid = blockIdx.x * 4 + (tid >> 6);   // n*512 + o
  int lane = tid & 63;
  int n = wid >> 9, o = wid & 511;
  const float* wr = w1 + (size_t)o * 2048 + 1024;
  const float* xr = xp + (size_t)n * 1024;
  float s = 0.f;
#pragma unroll
  for (int r = 0; r < 16; r++) { int c = lane + r * 64; s += wr[c] * xr[c]; }
#pragma unroll
  for (int off = 32; off >= 1; off >>= 1) s += __shfl_xor(s, off);
  if (lane == 0) bias1[wid] = s;
}

// ---- 3x3 weight prep -> tap-grouped blocked layout ----
// Wg2[tensor][ot(8)][ks(16)][slot u(2304)][8 bf16]:
//   u = g*768 + (dh*4+kg)*64 + o ; data = w[o0+o][ks*32+kg*8+j][dh*3+g]
__global__ __launch_bounds__(256) void wprep3_kernel(
    const float* __restrict__ w2, const float* __restrict__ wq,
    const float* __restrict__ wk, const float* __restrict__ wv,
    const float* __restrict__ wm, unsigned short* __restrict__ Wg2) {
  int ks = blockIdx.x, ot = blockIdx.y, tid = blockIdx.z;
  int t = threadIdx.x;
  const float* src;
  if (tid == 0) src = w2;
  else {
    int d = (tid - 1) >> 2, r = (tid - 1) & 3;
    src = (r == 0 ? wq : r == 1 ? wk : r == 2 ? wv : wm) + (size_t)d * W3SZ;
  }
  __shared__ unsigned short S[64 * 288];
  const float* sb = src + (size_t)ot * 64 * 4608 + (size_t)ks * 288;
  for (int j = 0; j < 72; j++) {
    int flat = j * 256 + t;          // < 18432
    int o = flat / 288, ci = flat % 288;
    S[flat] = f2b(sb[(size_t)o * 4608 + ci]);
  }
  __syncthreads();
  unsigned short* dst = Wg2 + (((size_t)(tid * 8 + ot) * 16 + ks) * 2304) * 8;
#pragma unroll
  for (int s = 0; s < 9; s++) {
    int u = t + s * 256;
    int g = u / 768, rem = u % 768;
    int rl = rem >> 6, o = rem & 63;
    int dh = rl >> 2, kg = rl & 3;
    int t9src = dh * 3 + g;
    bhalf8 v;
#pragma unroll
    for (int j = 0; j < 8; j++) v[j] = (short)S[o * 288 + (kg * 8 + j) * 9 + t9src];
    *(bhalf8*)(dst + (size_t)u * 8) = v;
  }
}

// ---- conv1 weight prep -> blocked: W1g[ot(8)][ks(32)][slot(256)][8] ----
__global__ void w1prep_kernel(const float* __restrict__ w1, unsigned short* __restrict__ W1g) {
  int ks = blockIdx.x, ot = blockIdx.y, t = threadIdx.x;
  int kg = t >> 6, o = t & 63;
  const float* s = w1 + (size_t)(ot * 64 + o) * 2048 + ks * 32 + kg * 8;
  bhalf8 v;
#pragma unroll
  for (int j = 0; j < 8; j++) v[j] = (short)f2b(s[j]);
  *(bhalf8*)(W1g + (((size_t)ot * 32 + ks) * 256 + t) * 8) = v;
}

// ---- feat transpose: feat[img][c][p] f32 -> featT[img][p][c] bf16 ----
__global__ __launch_bounds__(256) void ftprep_kernel(
    const float* __restrict__ feat, unsigned short* __restrict__ featT) {
  int img = blockIdx.z, c0 = blockIdx.y * 64, p0 = blockIdx.x * 64;
  int t = threadIdx.x;
  int a = t >> 6, b = t & 63;
  __shared__ float S[64][65];
#pragma unroll
  for (int j = 0; j < 16; j++) {
    int r = a * 16 + j;
    S[r][b] = feat[((size_t)img * 1024 + c0 + r) * 256 + p0 + b];
  }
  __syncthreads();
#pragma unroll
  for (int j = 0; j < 16; j++) {
    int pl = a * 16 + j;
    featT[((size_t)img * 256 + p0 + pl) * 1024 + c0 + b] = f2b(S[b][pl]);
  }
}

// ---------------------------------------------------------------------------
// Unified MFMA conv, depth-2 counted-vmcnt pipeline + setprio MFMA clusters.
// Grid: x = n (W-sharing blocks adjacent), y = ot*PSPLIT + pq.
// ---------------------------------------------------------------------------
template <int TAPS, int KTOT, int WAVES, int NREP, int PSPLIT,
          bool RELU, bool ADD, bool BIAS, bool VALID>
__global__ __launch_bounds__(WAVES * 64) void conv_mfma_kernel(
    const unsigned short* __restrict__ Xg, const int* __restrict__ rois,
    const unsigned short* __restrict__ Wg, const float* __restrict__ bias,
    unsigned short* __restrict__ Out) {
  constexpr int THREADS = WAVES * 64;
  constexpr int NK = KTOT / 32;
  static_assert(PSPLIT * WAVES * NREP * 16 == 256, "p coverage");

  int n = blockIdx.x;
  int ot = blockIdx.y / PSPLIT;
  int pq = blockIdx.y % PSPLIT;
  int t = threadIdx.x;
  int wv = t >> 6, l = t & 63, l15 = l & 15, l4 = l >> 4;
  int pbase = (pq * WAVES + wv) * (NREP * 16);
  const unsigned short* xb =
      Xg + (rois ? (size_t)rois[n * 5] * 256 * KTOT : (size_t)n * 256 * KTOT);
  floatx4 acc[4][NREP] = {};

  if constexpr (TAPS == 9) {
    constexpr int LW = 768 / THREADS;
    constexpr int LX = 1024 / THREADS;
    static_assert(768 % THREADS == 0 && 1024 % THREADS == 0, "stage div");
    __shared__ bhalf8 Xs[2][1024];
    __shared__ bhalf8 Wl[3][768];

    auto stageX = [&](int xbuf, int ks) {
#pragma unroll
      for (int i = 0; i < LX; i++) {
        int base = i * THREADS + wv * 64;
        int u = base + l;
        int p = u & 255, kg = u >> 8;
        gload_lds16(xb + (size_t)p * KTOT + ks * 32 + kg * 8, &Xs[xbuf][base]);
      }
    };
    auto stageW = [&](int wbuf, int ks, int g) {
      const unsigned short* wb =
          Wg + (((size_t)ot * NK + ks) * 2304 + g * 768) * 8;
#pragma unroll
      for (int i = 0; i < LW; i++) {
        int base = i * THREADS + wv * 64;
        gload_lds16(wb + (size_t)(base + l) * 8, &Wl[wbuf][base]);
      }
    };
    auto computeG = [&](const bhalf8* X, const bhalf8* W, int g) {
      bhalf8 BW[NREP + 2];
#pragma unroll
      for (int w10 = 0; w10 < NREP + 2; w10++) {
        int row = (pbase + w10 * 16 + l15 + g) & 255;
        BW[w10] = X[l4 * 256 + row];
      }
      bhalf8 A[3][4];
#pragma unroll
      for (int dh = 0; dh < 3; dh++)
#pragma unroll
        for (int of = 0; of < 4; of++)
          A[dh][of] = W[(dh * 4 + l4) * 64 + of * 16 + l15];
      __builtin_amdgcn_s_setprio(1);
#pragma unroll
      for (int dh = 0; dh < 3; dh++)
#pragma unroll
        for (int of = 0; of < 4; of++)
#pragma unroll
          for (int pf = 0; pf < NREP; pf++)
            acc[of][pf] = __builtin_amdgcn_mfma_f32_16x16x32_bf16(
                A[dh][of], BW[pf + dh], acc[of][pf], 0, 0, 0);
      __builtin_amdgcn_s_setprio(0);
    };

    stageW(0, 0, 0); stageX(0, 0);
    stageW(1, 0, 1);

    for (int ks = 0; ks < NK - 1; ks++) {
      const bhalf8* X = Xs[ks & 1];
      stageW(2, ks, 2);
      waitvm<2 * LW>();
      phase_barrier_pre();
      computeG(X, Wl[0], 0);
      phase_barrier_post();
      stageW(0, ks + 1, 0); stageX((ks + 1) & 1, ks + 1);
      waitvm<2 * LW + LX>();
      phase_barrier_pre();
      computeG(X, Wl[1], 1);
      phase_barrier_post();
      stageW(1, ks + 1, 1);
      waitvm<2 * LW + LX>();
      phase_barrier_pre();
      computeG(X, Wl[2], 2);
      phase_barrier_post();
    }
    {
      const bhalf8* X = Xs[(NK - 1) & 1];
      stageW(2, NK - 1, 2);
      waitvm<2 * LW>();
      phase_barrier_pre();
      computeG(X, Wl[0], 0);
      phase_barrier_post();
      waitvm<LW>();
      phase_barrier_pre();
      computeG(X, Wl[1], 1);
      phase_barrier_post();
      waitvm<0>();
      phase_barrier_pre();
      computeG(X, Wl[2], 2);
      phase_barrier_post();
    }
  } else {
    constexpr int LW = 256 / THREADS;
    constexpr int LX = 1024 / THREADS;
    static_assert(256 % THREADS == 0 && 1024 % THREADS == 0, "stage div");
    __shared__ bhalf8 Xs[3][1024];
    __shared__ bhalf8 Wl[3][256];

    auto stage1 = [&](int b, int ks) {
#pragma unroll
      for (int i = 0; i < LX; i++) {
        int base = i * THREADS + wv * 64;
        int u = base + l;
        int p = u & 255, kg = u >> 8;
        gload_lds16(xb + (size_t)p * KTOT + ks * 32 + kg * 8, &Xs[b][base]);
      }
      const unsigned short* wb = Wg + (((size_t)ot * NK + ks) * 256) * 8;
#pragma unroll
      for (int i = 0; i < LW; i++) {
        int base = i * THREADS + wv * 64;
        gload_lds16(wb + (size_t)(base + l) * 8, &Wl[b][base]);
      }
    };
    auto compute1 = [&](const bhalf8* X, const bhalf8* W) {
      bhalf8 B[NREP];
#pragma unroll
      for (int pf = 0; pf < NREP; pf++) {
        int row = (pbase + pf * 16 + l15) & 255;
        B[pf] = X[l4 * 256 + row];
      }
      bhalf8 A[4];
#pragma unroll
      for (int of = 0; of < 4; of++) A[of] = W[l4 * 64 + of * 16 + l15];
      __builtin_amdgcn_s_setprio(1);
#pragma unroll
      for (int of = 0; of < 4; of++)
#pragma unroll
        for (int pf = 0; pf < NREP; pf++)
          acc[of][pf] = __builtin_amdgcn_mfma_f32_16x16x32_bf16(
              A[of], B[pf], acc[of][pf], 0, 0, 0);
      __builtin_amdgcn_s_setprio(0);
    };

    stage1(0, 0);
    stage1(1, 1);
    int b = 0;
    for (int ks = 0; ks < NK - 2; ks++) {
      int b2 = b + 2; if (b2 >= 3) b2 -= 3;
      stage1(b2, ks + 2);
      waitvm<2 * (LW + LX)>();
      phase_barrier_pre();
      compute1(Xs[b], Wl[b]);
      phase_barrier_post();
      b = b + 1; if (b >= 3) b -= 3;
    }
    waitvm<LW + LX>();
    phase_barrier_pre();
    compute1(Xs[b], Wl[b]);
    phase_barrier_post();
    b = b + 1; if (b >= 3) b -= 3;
    waitvm<0>();
    phase_barrier_pre();
    compute1(Xs[b], Wl[b]);
    phase_barrier_post();
  }

#pragma unroll
  for (int of = 0; of < 4; of++) {
    int og = ot * 64 + of * 16 + l4 * 4;
    int tensor = og >> 9, ol = og & 511;
#pragma unroll
    for (int pf = 0; pf < NREP; pf++) {
      int p = pbase + pf * 16 + l15;
      int po = p;
      if (VALID) {
        int h = p >> 4, w = p & 15;
        if (h >= 14 || w >= 14) continue;
        po = (h + 1) * 16 + (w + 1);
      }
      unsigned short* dp = Out + (((size_t)tensor * 32 + n) * 256 + po) * 512 + ol;
      float vv[4];
#pragma unroll
      for (int r2 = 0; r2 < 4; r2++) vv[r2] = acc[of][pf][r2];
      if (BIAS) {
#pragma unroll
        for (int r2 = 0; r2 < 4; r2++) vv[r2] += bias[(size_t)n * 512 + ol + r2];
      }
      if (ADD) {
        ushort4 old = *(const ushort4*)dp;
        vv[0] += b2f(old.x); vv[1] += b2f(old.y); vv[2] += b2f(old.z); vv[3] += b2f(old.w);
      }
      if (RELU) {
#pragma unroll
        for (int r2 = 0; r2 < 4; r2++) vv[r2] = fmaxf(vv[r2], 0.f);
      }
      ushort4 st = { f2b(vv[0]), f2b(vv[1]), f2b(vv[2]), f2b(vv[3]) };
      *(ushort4*)dp = st;
    }
  }
}

// ---- V transpose: bufv[kn][pp][c] -> vt[ppc][c][kn]  (interior pp only) ----
__global__ __launch_bounds__(256) void vtrans_kernel(
    const unsigned short* __restrict__ v, unsigned short* __restrict__ vt) {
  int ppc = blockIdx.x;                       // 0..195
  int pp = (ppc / 14 + 1) * 16 + ppc % 14 + 1;
  int t = threadIdx.x;
  __shared__ unsigned short S[32 * 512];
#pragma unroll
  for (int i = 0; i < 8; i++) {
    int u = i * 256 + t;
    int kn = u >> 6, c8 = (u & 63) * 8;
    *(bhalf8*)&S[kn * 512 + c8] = *(const bhalf8*)(v + ((size_t)kn * 256 + pp) * 512 + c8);
  }
  __syncthreads();
#pragma unroll
  for (int half = 0; half < 2; half++) {
    int c = half * 256 + t;
    unsigned int col[16];
#pragma unroll
    for (int j = 0; j < 16; j++)
      col[j] = (unsigned int)S[(2 * j) * 512 + c] |
               ((unsigned int)S[(2 * j + 1) * 512 + c] << 16);
    unsigned short* dst = vt + ((size_t)ppc * 512 + c) * 32;
#pragma unroll
    for (int j = 0; j < 4; j++) {
      uint4 P = { col[j * 4], col[j * 4 + 1], col[j * 4 + 2], col[j * 4 + 3] };
      *(uint4*)(dst + j * 8) = P;
    }
  }
}

// ---------------------------------------------------------------------------
// Fused attention per pixel: QK^T (MFMA) -> in-register softmax -> PV (MFMA,
// C^T form via pre-transposed V) -> store vf + GroupNorm partials.
// ---------------------------------------------------------------------------
__global__ __launch_bounds__(64) void attfused_kernel(
    const unsigned short* __restrict__ q, const unsigned short* __restrict__ k,
    const unsigned short* __restrict__ vt, unsigned short* __restrict__ out,
    float* __restrict__ gnpart) {
  int pp = blockIdx.x;
  int h = pp >> 4, w = pp & 15;
  int l = threadIdx.x, l15 = l & 15, l4 = l >> 4;
  if (h < 1 || h > 14 || w < 1 || w > 14) {
    uint4 z = {0u, 0u, 0u, 0u};
#pragma unroll
    for (int qn = 0; qn < 32; qn++)
      *(uint4*)(out + ((size_t)qn * 256 + pp) * 512 + l * 8) = z;
    return;
  }
  int ppc = (h - 1) * 14 + (w - 1);

  // ---- QK^T: C[kn32][qn32], K=512 ----
  floatx4 sc[2][2] = {};
#pragma unroll
  for (int kb = 0; kb < 16; kb++) {
    bhalf8 A[2], B[2];
#pragma unroll
    for (int of = 0; of < 2; of++)
      A[of] = *(const bhalf8*)(k + ((size_t)(of * 16 + l15) * 256 + pp) * 512 + kb * 32 + l4 * 8);
#pragma unroll
    for (int pf = 0; pf < 2; pf++)
      B[pf] = *(const bhalf8*)(q + ((size_t)(pf * 16 + l15) * 256 + pp) * 512 + kb * 32 + l4 * 8);
#pragma unroll
    for (int of = 0; of < 2; of++)
#pragma unroll
      for (int pf = 0; pf < 2; pf++)
        sc[of][pf] = __builtin_amdgcn_mfma_f32_16x16x32_bf16(A[of], B[pf], sc[of][pf], 0, 0, 0);
  }

  // ---- softmax over kn (rows), per qn column; P -> LDS bf16 normalized ----
  __shared__ unsigned short p_lds[32 * 32];
  const float scale = 0.044194173824159216f;
#pragma unroll
  for (int pf = 0; pf < 2; pf++) {
    float v8[8];
    float m = -3.4e38f;
#pragma unroll
    for (int of = 0; of < 2; of++)
#pragma unroll
      for (int r = 0; r < 4; r++) {
        float x = sc[of][pf][r] * scale;
        v8[of * 4 + r] = x;
        m = fmaxf(m, x);
      }
    m = fmaxf(m, __shfl_xor(m, 16));
    m = fmaxf(m, __shfl_xor(m, 32));
    float s = 0.f;
#pragma unroll
    for (int i = 0; i < 8; i++) { v8[i] = __expf(v8[i] - m); s += v8[i]; }
    s += __shfl_xor(s, 16);
    s += __shfl_xor(s, 32);
    float inv = 1.f / s;
#pragma unroll
    for (int of = 0; of < 2; of++) {
      ushort4 pk = { f2b(v8[of * 4 + 0] * inv), f2b(v8[of * 4 + 1] * inv),
                     f2b(v8[of * 4 + 2] * inv), f2b(v8[of * 4 + 3] * inv) };
      *(ushort4*)&p_lds[(pf * 16 + l15) * 32 + of * 16 + l4 * 4] = pk;
    }
  }

  // ---- PV as C^T: C[c512][qn32] = VT[c][kn] @ P[qn][kn]^T, K=32 ----
  bhalf8 PB[2];
#pragma unroll
  for (int qf = 0; qf < 2; qf++)
    PB[qf] = *(const bhalf8*)&p_lds[(qf * 16 + l15) * 32 + l4 * 8];
  float gs[2] = {0.f, 0.f}, gss[2] = {0.f, 0.f};
  const unsigned short* vtb = vt + (size_t)ppc * 512 * 32;
#pragma unroll
  for (int chunk = 0; chunk < 4; chunk++) {
    bhalf8 VA[8];
#pragma unroll
    for (int co = 0; co < 8; co++)
      VA[co] = *(const bhalf8*)(vtb + (size_t)(chunk * 128 + co * 16 + l15) * 32 + l4 * 8);
#pragma unroll
    for (int co = 0; co < 8; co++)
#pragma unroll
      for (int qf = 0; qf < 2; qf++) {
        floatx4 pa = __builtin_amdgcn_mfma_f32_16x16x32_bf16(
            VA[co], PB[qf], (floatx4){0.f, 0.f, 0.f, 0.f}, 0, 0, 0);
        float x0 = pa[0], x1 = pa[1], x2 = pa[2], x3 = pa[3];
        gs[qf] += x0 + x1 + x2 + x3;
        gss[qf] += x0 * x0 + x1 * x1 + x2 * x2 + x3 * x3;
        ushort4 st = { f2b(x0), f2b(x1), f2b(x2), f2b(x3) };
        int qn = qf * 16 + l15;
        int c = chunk * 128 + co * 16 + l4 * 4;
        *(ushort4*)(out + ((size_t)qn * 256 + pp) * 512 + c) = st;
      }
  }
#pragma unroll
  for (int qf = 0; qf < 2; qf++) {
    gs[qf] += __shfl_xor(gs[qf], 16);  gs[qf] += __shfl_xor(gs[qf], 32);
    gss[qf] += __shfl_xor(gss[qf], 16); gss[qf] += __shfl_xor(gss[qf], 32);
  }
  if (l4 == 0) {
#pragma unroll
    for (int qf = 0; qf < 2; qf++) {
      int qn = qf * 16 + l15;
      gnpart[((size_t)ppc * 32 + qn) * 2]     = gs[qf];
      gnpart[((size_t)ppc * 32 + qn) * 2 + 1] = gss[qf];
    }
  }
}

// ---- GroupNorm: reduce partials + apply affine + relu (interior only) ----
__global__ __launch_bounds__(256) void gnapply3_kernel(
    unsigned short* __restrict__ x, const float* __restrict__ gnpart,
    const float* __restrict__ gamma, const float* __restrict__ beta) {
  int n = blockIdx.y, half = blockIdx.x, t = threadIdx.x;
  float s = 0.f, ss = 0.f;
  if (t < 196) {
    s  = gnpart[((size_t)t * 32 + n) * 2];
    ss = gnpart[((size_t)t * 32 + n) * 2 + 1];
  }
#pragma unroll
  for (int off = 32; off >= 1; off >>= 1) { s += __shfl_xor(s, off); ss += __shfl_xor(ss, off); }
  __shared__ float sm[8];
  int wv = t >> 6, ln = t & 63;
  if (ln == 0) { sm[wv] = s; sm[4 + wv] = ss; }
  __syncthreads();
  float S = sm[0] + sm[1] + sm[2] + sm[3];
  float SS = sm[4] + sm[5] + sm[6] + sm[7];
  const float M = 512.f * 196.f;
  float mu = S / M;
  float var = SS / M - mu * mu;
  float inv = rsqrtf(var + 1e-5f);
  int c2 = t * 2;
  unsigned short* xb = x + (size_t)n * ACT_N;
  float g0 = gamma[c2], g1 = gamma[c2 + 1];
  float be0 = beta[c2], be1 = beta[c2 + 1];
  for (int i = 0; i < 98; i++) {
    int ppc = half * 98 + i;
    int pp = (ppc / 14 + 1) * 16 + ppc % 14 + 1;
    unsigned int vv = *(unsigned int*)(xb + pp * 512 + c2);
    float a = (b2f((unsigned short)vv) - mu) * inv * g0 + be0;
    float b = (b2f((unsigned short)(vv >> 16)) - mu) * inv * g1 + be1;
    a = fmaxf(a, 0.f); b = fmaxf(b, 0.f);
    *(unsigned int*)(xb + pp * 512 + c2) =
        (unsigned int)f2b(a) | ((unsigned int)f2b(b) << 16);
  }
}

// ---- final: mean over interior 196 -> out[n][1024+c] (f32) ----
__global__ void fmean2_kernel(const unsigned short* __restrict__ x, float* __restrict__ out) {
  int n = blockIdx.x, t = threadIdx.x;
  const unsigned short* xb = x + (size_t)n * ACT_N;
  float s0 = 0.f, s1 = 0.f;
  for (int i = 0; i < 196; i++) {
    int pp = (i / 14 + 1) * 16 + (i % 14) + 1;
    unsigned int vv = *(const unsigned int*)(xb + pp * 512 + t * 2);
    s0 += b2f((unsigned short)vv);
    s1 += b2f((unsigned short)(vv >> 16));
  }
  out[(size_t)n * 1536 + 1024 + t * 2]     = s0 * (1.f / 196.f);
  out[(size_t)n * 1536 + 1024 + t * 2 + 1] = s1 * (1.f / 196.f);
}

extern "C" void kernel_launch(void* const* d_in, const int* in_sizes, int n_in,
                              void* d_out, int out_size, void* d_ws, size_t ws_size,
                              hipStream_t stream) {
  const float* x     = (const float*)d_in[0];
  const float* feat  = (const float*)d_in[1];
  const int*   rois  = (const int*)d_in[2];
  const float* w1    = (const float*)d_in[3];
  const float* w2    = (const float*)d_in[4];
  const float* wq    = (const float*)d_in[5];
  const float* wk    = (const float*)d_in[6];
  const float* wv    = (const float*)d_in[7];
  const float* wm    = (const float*)d_in[8];
  const float* gamma = (const float*)d_in[9];
  const float* beta  = (const float*)d_in[10];
  float* out = (float*)d_out;

  // ---- workspace layout ----
  // vt (6.42 MB) ALIASES [xp..W1g]: those are only used before the d-loop.
  float* wsf   = (float*)d_ws;
  float* xp    = wsf;                // 32768 f32
  float* bias1 = xp + 32768;         // 16384 f32
  float* stats = bias1 + 16384;      // 64 f32 (layout keep)
  float* attf  = stats + 64;         // 262144 f32 (layout keep)
  unsigned short* ub    = (unsigned short*)(attf + 262144);
  unsigned short* featT = ub;                    // 2097152 shorts
  unsigned short* W1g   = featT + 2097152;       // 524288 shorts
  unsigned short* Wg2   = W1g + 524288;          // 13*W3SZ shorts
  unsigned short* bufq  = Wg2 + 30670848;        // q/k/v contiguous
  unsigned short* bufk  = bufq + 4194304;
  unsigned short* bufv  = bufk + 4194304;
  unsigned short* bufx  = bufv + 4194304;
  unsigned short* vt    = (unsigned short*)d_ws; // 196*512*32 shorts
  float* gnpart = (float*)(bufx + 4194304);      // 196*32*2 f32

  // bufx border rows must be zero (only interior ever written by convs)
  hipMemsetAsync(bufx, 0, (size_t)4194304 * 2, stream);

  pool_max_kernel<<<8192, 256, 0, stream>>>(x, xp, out);
  bias1_kernel<<<4096, 256, 0, stream>>>(w1, xp, bias1);
  wprep3_kernel<<<dim3(16, 8, 13), 256, 0, stream>>>(w2, wq, wk, wv, wm, Wg2);
  w1prep_kernel<<<dim3(32, 8), 256, 0, stream>>>(w1, W1g);
  ftprep_kernel<<<dim3(4, 16, 8), 256, 0, stream>>>(feat, featT);

  // conv1: 1x1, K=1024, +bias1, relu, full 16x16 output -> bufq
  conv_mfma_kernel<1, 1024, 4, 4, 1, true, false, true, false>
      <<<dim3(32, 8), 256, 0, stream>>>(featT, rois, W1g, bias1, bufq);
  // conv2: valid 3x3 -> padded interior of bufx, relu
  conv_mfma_kernel<9, 512, 4, 4, 1, true, false, false, true>
      <<<dim3(32, 8), 256, 0, stream>>>(bufq, nullptr, Wg2, nullptr, bufx);

  for (int d = 0; d < 3; d++) {
    // q,k,v batched conv
    conv_mfma_kernel<9, 512, 4, 4, 1, false, false, false, true>
        <<<dim3(32, 24), 256, 0, stream>>>(bufx, nullptr,
            Wg2 + (size_t)(1 + 4 * d) * W3SZ, nullptr, bufq);
    vtrans_kernel<<<196, 256, 0, stream>>>(bufv, vt);
    attfused_kernel<<<256, 64, 0, stream>>>(bufq, bufk, vt, bufq, gnpart);
    gnapply3_kernel<<<dim3(2, 32), 256, 0, stream>>>(bufq, gnpart,
        gamma + d * 512, beta + d * 512);
    // wm conv + residual add into bufx
    conv_mfma_kernel<9, 512, 4, 4, 1, false, true, false, true>
        <<<dim3(32, 8), 256, 0, stream>>>(bufq, nullptr,
            Wg2 + (size_t)(4 + 4 * d) * W3SZ, nullptr, bufx);
  }

  fmean2_kernel<<<32, 256, 0, stream>>>(bufx, out);
}

// Round 12
// 681.151 us; speedup vs baseline: 1.3054x; 1.1256x over previous
//
#include <hip/hip_runtime.h>

// ---------------------------------------------------------------------------
// ACARHead forward. bf16-MFMA convs with REGISTER PING-PONG phases:
// per phase: [ldregs(next) ; stage(f+2) ; MFMA(cur) ; waitvm ; barrier]
// so LDS reads drain under the MFMA cluster. W staged via global_load_lds
// into 3 rotating LDS buffers (buffer = tap-group g); X double-buffered.
// Fused MFMA attention (QK^T -> in-register softmax -> PV) + GN partials.
// Grid order x=n, y=ot so same-W blocks are XCD-L2-adjacent.
// Activation layout: bf16 [n][p=256][c]; 14x14 payload at rows/cols 1..14.
// ---------------------------------------------------------------------------

typedef __attribute__((ext_vector_type(8))) short bhalf8;
typedef __attribute__((ext_vector_type(4))) float floatx4;

#define ACT_N 131072   // 256*512 bf16 elements per sample
#define W3SZ  2359296  // 512*512*9 (also = blocked per-tensor short count)

__device__ inline float b2f(unsigned short u) {
  union { unsigned int i; float f; } x; x.i = ((unsigned int)u) << 16; return x.f;
}
__device__ inline unsigned short f2b(float f) {
  union { float f; unsigned int i; } x; x.f = f;
  return (unsigned short)((x.i + 0x7FFFu + ((x.i >> 16) & 1u)) >> 16);
}
__device__ inline void gload_lds16(const unsigned short* g, bhalf8* l) {
  __builtin_amdgcn_global_load_lds(
      (const __attribute__((address_space(1))) unsigned int*)(const void*)g,
      (__attribute__((address_space(3))) unsigned int*)(void*)l, 16, 0, 0);
}
template <int N> __device__ inline void waitvm() {
  asm volatile("s_waitcnt vmcnt(%0)" :: "i"(N) : "memory");
}
__device__ inline void SB() { __builtin_amdgcn_sched_barrier(0); }
__device__ inline void endphase() {  // drain own stages, then block barrier
  SB(); waitvm<0>();
  __builtin_amdgcn_s_barrier();
  SB();
}

// ---- AdaptiveMaxPool3d(1): max over 196, write xp (f32) and out[:,0:1024] ----
__global__ void pool_max_kernel(const float* __restrict__ x, float* __restrict__ xp,
                                float* __restrict__ out) {
  int tid = threadIdx.x;
  int wid = blockIdx.x * 4 + (tid >> 6);   // n*1024 + c
  int lane = tid & 63;
  int n = wid >> 10, c = wid & 1023;
  const float* p = x + (size_t)wid * 196;
  float v = -3.4e38f;
  v = fmaxf(v, p[lane]);
  v = fmaxf(v, p[lane + 64]);
  v = fmaxf(v, p[lane + 128]);
  if (lane < 4) v = fmaxf(v, p[lane + 192]);
#pragma unroll
  for (int off = 32; off >= 1; off >>= 1) v = fmaxf(v, __shfl_xor(v, off));
  if (lane == 0) { xp[wid] = v; out[(size_t)n * 1536 + c] = v; }
}

// ---- bias1[n][o] = sum_{c<1024} w1[o][1024+c] * xp[n][c]  (f32) ----
__global__ void bias1_kernel(const float* __restrict__ w1, const float* __restrict__ xp,
                             float* __restrict__ bias1) {
  int tid = threadIdx.x;
  int wid = blockIdx.x * 4 + (tid >> 6);   // n*512 + o
  int lane = tid & 63;
  int n = wid >> 9, o = wid & 511;
  const float* wr = w1 + (size_t)o * 2048 + 1024;
  const float* xr = xp + (size_t)n * 1024;
  float s = 0.f;
#pragma unroll
  for (int r = 0; r < 16; r++) { int c = lane + r * 64; s += wr[c] * xr[c]; }
#pragma unroll
  for (int off = 32; off >= 1; off >>= 1) s += __shfl_xor(s, off);
  if (lane == 0) bias1[wid] = s;
}

// ---- 3x3 weight prep -> tap-grouped blocked layout ----
// Wg2[tensor][ot(8)][ks(16)][slot u(2304)][8 bf16]:
//   u = g*768 + (dh*4+kg)*64 + o ; data = w[o0+o][ks*32+kg*8+j][dh*3+g]
__global__ __launch_bounds__(256) void wprep3_kernel(
    const float* __restrict__ w2, const float* __restrict__ wq,
    const float* __restrict__ wk, const float* __restrict__ wv,
    const float* __restrict__ wm, unsigned short* __restrict__ Wg2) {
  int ks = blockIdx.x, ot = blockIdx.y, tid = blockIdx.z;
  int t = threadIdx.x;
  const float* src;
  if (tid == 0) src = w2;
  else {
    int d = (tid - 1) >> 2, r = (tid - 1) & 3;
    src = (r == 0 ? wq : r == 1 ? wk : r == 2 ? wv : wm) + (size_t)d * W3SZ;
  }
  __shared__ unsigned short S[64 * 288];
  const float* sb = src + (size_t)ot * 64 * 4608 + (size_t)ks * 288;
  for (int j = 0; j < 72; j++) {
    int flat = j * 256 + t;          // < 18432
    int o = flat / 288, ci = flat % 288;
    S[flat] = f2b(sb[(size_t)o * 4608 + ci]);
  }
  __syncthreads();
  unsigned short* dst = Wg2 + (((size_t)(tid * 8 + ot) * 16 + ks) * 2304) * 8;
#pragma unroll
  for (int s = 0; s < 9; s++) {
    int u = t + s * 256;
    int g = u / 768, rem = u % 768;
    int rl = rem >> 6, o = rem & 63;
    int dh = rl >> 2, kg = rl & 3;
    int t9src = dh * 3 + g;
    bhalf8 v;
#pragma unroll
    for (int j = 0; j < 8; j++) v[j] = (short)S[o * 288 + (kg * 8 + j) * 9 + t9src];
    *(bhalf8*)(dst + (size_t)u * 8) = v;
  }
}

// ---- conv1 weight prep -> blocked: W1g[ot(8)][ks(32)][slot(256)][8] ----
__global__ void w1prep_kernel(const float* __restrict__ w1, unsigned short* __restrict__ W1g) {
  int ks = blockIdx.x, ot = blockIdx.y, t = threadIdx.x;
  int kg = t >> 6, o = t & 63;
  const float* s = w1 + (size_t)(ot * 64 + o) * 2048 + ks * 32 + kg * 8;
  bhalf8 v;
#pragma unroll
  for (int j = 0; j < 8; j++) v[j] = (short)f2b(s[j]);
  *(bhalf8*)(W1g + (((size_t)ot * 32 + ks) * 256 + t) * 8) = v;
}

// ---- feat transpose: feat[img][c][p] f32 -> featT[img][p][c] bf16 ----
__global__ __launch_bounds__(256) void ftprep_kernel(
    const float* __restrict__ feat, unsigned short* __restrict__ featT) {
  int img = blockIdx.z, c0 = blockIdx.y * 64, p0 = blockIdx.x * 64;
  int t = threadIdx.x;
  int a = t >> 6, b = t & 63;
  __shared__ float S[64][65];
#pragma unroll
  for (int j = 0; j < 16; j++) {
    int r = a * 16 + j;
    S[r][b] = feat[((size_t)img * 1024 + c0 + r) * 256 + p0 + b];
  }
  __syncthreads();
#pragma unroll
  for (int j = 0; j < 16; j++) {
    int pl = a * 16 + j;
    featT[((size_t)img * 256 + p0 + pl) * 1024 + c0 + b] = f2b(S[b][pl]);
  }
}

// ---------------------------------------------------------------------------
// Unified MFMA conv, register ping-pong phases. Grid: x=n, y=ot*PSPLIT+pq.
// ---------------------------------------------------------------------------
template <int TAPS, int KTOT, int WAVES, int NREP, int PSPLIT,
          bool RELU, bool ADD, bool BIAS, bool VALID>
__global__ __launch_bounds__(WAVES * 64, 2) void conv_mfma_kernel(
    const unsigned short* __restrict__ Xg, const int* __restrict__ rois,
    const unsigned short* __restrict__ Wg, const float* __restrict__ bias,
    unsigned short* __restrict__ Out) {
  constexpr int THREADS = WAVES * 64;
  constexpr int NK = KTOT / 32;
  static_assert(PSPLIT * WAVES * NREP * 16 == 256, "p coverage");
  static_assert((NK & 1) == 0, "even NK");

  int n = blockIdx.x;
  int ot = blockIdx.y / PSPLIT;
  int pq = blockIdx.y % PSPLIT;
  int t = threadIdx.x;
  int wv = t >> 6, l = t & 63, l15 = l & 15, l4 = l >> 4;
  int pbase = (pq * WAVES + wv) * (NREP * 16);
  const unsigned short* xb =
      Xg + (rois ? (size_t)rois[n * 5] * 256 * KTOT : (size_t)n * 256 * KTOT);
  floatx4 acc[4][NREP] = {};

  if constexpr (TAPS == 9) {
    constexpr int LX = 1024 / THREADS;
    static_assert(768 % THREADS == 0 && 1024 % THREADS == 0, "stage div");
    __shared__ bhalf8 Xs[2][1024];
    __shared__ bhalf8 Wl[3][768];

    auto stageX = [&](int xbuf, int ks) {
#pragma unroll
      for (int i = 0; i < LX; i++) {
        int base = i * THREADS + wv * 64;
        int u = base + l;
        int p = u & 255, kg = u >> 8;
        gload_lds16(xb + (size_t)p * KTOT + ks * 32 + kg * 8, &Xs[xbuf][base]);
      }
    };
    auto stageW = [&](int wbuf, int ks, int g) {
      const unsigned short* wb =
          Wg + (((size_t)ot * NK + ks) * 2304 + g * 768) * 8;
#pragma unroll
      for (int i = 0; i < 768 / THREADS; i++) {
        int base = i * THREADS + wv * 64;
        gload_lds16(wb + (size_t)(base + l) * 8, &Wl[wbuf][base]);
      }
    };
    auto ldregs = [&](bhalf8 (&BW)[NREP + 2], bhalf8 (&A)[12], int ks, int g) {
      const bhalf8* X = Xs[ks & 1];
#pragma unroll
      for (int w10 = 0; w10 < NREP + 2; w10++)
        BW[w10] = X[l4 * 256 + ((pbase + w10 * 16 + l15 + g) & 255)];
      const bhalf8* W = Wl[g];
#pragma unroll
      for (int dh = 0; dh < 3; dh++)
#pragma unroll
        for (int of = 0; of < 4; of++)
          A[dh * 4 + of] = W[(dh * 4 + l4) * 64 + of * 16 + l15];
    };
    auto domfma = [&](bhalf8 (&BW)[NREP + 2], bhalf8 (&A)[12]) {
      __builtin_amdgcn_s_setprio(1);
#pragma unroll
      for (int dh = 0; dh < 3; dh++)
#pragma unroll
        for (int of = 0; of < 4; of++)
#pragma unroll
          for (int pf = 0; pf < NREP; pf++)
            acc[of][pf] = __builtin_amdgcn_mfma_f32_16x16x32_bf16(
                A[dh * 4 + of], BW[pf + dh], acc[of][pf], 0, 0, 0);
      __builtin_amdgcn_s_setprio(0);
    };

    bhalf8 BW0[NREP + 2], A0[12], BW1[NREP + 2], A1[12];

    // prologue
    stageX(0, 0); stageW(0, 0, 0);
    endphase();
    ldregs(BW0, A0, 0, 0); SB();
    stageW(1, 0, 1); stageX(1, 1);
    endphase();

    for (int ks = 0; ks < NK; ks += 2) {
      // f=(ks,0): R0 computes; load (ks,1) into R1; stage W(ks,2)->buf2
      ldregs(BW1, A1, ks, 1); SB();
      stageW(2, ks, 2); SB();
      domfma(BW0, A0); endphase();
      // f=(ks,1): R1 computes; load (ks,2) into R0; stage W(ks+1,0)->buf0
      ldregs(BW0, A0, ks, 2); SB();
      stageW(0, ks + 1, 0); SB();
      domfma(BW1, A1); endphase();
      // f=(ks,2): R0 computes; load (ks+1,0) into R1; stage W(ks+1,1)->buf1, X(ks+2)
      ldregs(BW1, A1, ks + 1, 0); SB();
      stageW(1, ks + 1, 1);
      if (ks + 2 < NK) stageX(ks & 1, ks + 2);
      SB();
      domfma(BW0, A0); endphase();
      // f=(ks+1,0): R1 computes; load (ks+1,1) into R0; stage W(ks+1,2)->buf2
      ldregs(BW0, A0, ks + 1, 1); SB();
      stageW(2, ks + 1, 2); SB();
      domfma(BW1, A1); endphase();
      // f=(ks+1,1): R0 computes; load (ks+1,2) into R1; stage W(ks+2,0)->buf0
      ldregs(BW1, A1, ks + 1, 2); SB();
      if (ks + 2 < NK) stageW(0, ks + 2, 0);
      SB();
      domfma(BW0, A0); endphase();
      // f=(ks+1,2): R1 computes; load (ks+2,0) into R0; stage W(ks+2,1)->buf1, X(ks+3)
      if (ks + 2 < NK) { ldregs(BW0, A0, ks + 2, 0); SB(); }
      if (ks + 2 < NK) stageW(1, ks + 2, 1);
      if (ks + 3 < NK) stageX((ks + 1) & 1, ks + 3);
      SB();
      domfma(BW1, A1); endphase();
    }
  } else {
    constexpr int LX = 1024 / THREADS;
    static_assert(256 % THREADS == 0 && 1024 % THREADS == 0, "stage div");
    __shared__ bhalf8 Xs[3][1024];
    __shared__ bhalf8 Wl[3][256];

    auto stage1 = [&](int b, int ks) {
#pragma unroll
      for (int i = 0; i < LX; i++) {
        int base = i * THREADS + wv * 64;
        int u = base + l;
        int p = u & 255, kg = u >> 8;
        gload_lds16(xb + (size_t)p * KTOT + ks * 32 + kg * 8, &Xs[b][base]);
      }
      const unsigned short* wb = Wg + (((size_t)ot * NK + ks) * 256) * 8;
#pragma unroll
      for (int i = 0; i < 256 / THREADS; i++) {
        int base = i * THREADS + wv * 64;
        gload_lds16(wb + (size_t)(base + l) * 8, &Wl[b][base]);
      }
    };
    auto ldregs1 = [&](bhalf8 (&B)[NREP], bhalf8 (&A)[4], int ks) {
      const bhalf8* X = Xs[ks % 3];
#pragma unroll
      for (int pf = 0; pf < NREP; pf++)
        B[pf] = X[l4 * 256 + ((pbase + pf * 16 + l15) & 255)];
      const bhalf8* W = Wl[ks % 3];
#pragma unroll
      for (int of = 0; of < 4; of++) A[of] = W[l4 * 64 + of * 16 + l15];
    };
    auto domfma1 = [&](bhalf8 (&B)[NREP], bhalf8 (&A)[4]) {
      __builtin_amdgcn_s_setprio(1);
#pragma unroll
      for (int of = 0; of < 4; of++)
#pragma unroll
        for (int pf = 0; pf < NREP; pf++)
          acc[of][pf] = __builtin_amdgcn_mfma_f32_16x16x32_bf16(
              A[of], B[pf], acc[of][pf], 0, 0, 0);
      __builtin_amdgcn_s_setprio(0);
    };

    bhalf8 B0[NREP], A0[4], B1[NREP], A1[4];
    stage1(0, 0);
    endphase();
    ldregs1(B0, A0, 0); SB();
    stage1(1, 1);
    endphase();
    for (int ks = 0; ks < NK; ks += 2) {
      ldregs1(B1, A1, ks + 1); SB();
      if (ks + 2 < NK) stage1((ks + 2) % 3, ks + 2);
      SB();
      domfma1(B0, A0); endphase();
      if (ks + 2 < NK) { ldregs1(B0, A0, ks + 2); SB(); }
      if (ks + 3 < NK) stage1((ks + 3) % 3, ks + 3);
      SB();
      domfma1(B1, A1); endphase();
    }
  }

#pragma unroll
  for (int of = 0; of < 4; of++) {
    int og = ot * 64 + of * 16 + l4 * 4;
    int tensor = og >> 9, ol = og & 511;
#pragma unroll
    for (int pf = 0; pf < NREP; pf++) {
      int p = pbase + pf * 16 + l15;
      int po = p;
      if (VALID) {
        int h = p >> 4, w = p & 15;
        if (h >= 14 || w >= 14) continue;
        po = (h + 1) * 16 + (w + 1);
      }
      unsigned short* dp = Out + (((size_t)tensor * 32 + n) * 256 + po) * 512 + ol;
      float vv[4];
#pragma unroll
      for (int r2 = 0; r2 < 4; r2++) vv[r2] = acc[of][pf][r2];
      if (BIAS) {
#pragma unroll
        for (int r2 = 0; r2 < 4; r2++) vv[r2] += bias[(size_t)n * 512 + ol + r2];
      }
      if (ADD) {
        ushort4 old = *(const ushort4*)dp;
        vv[0] += b2f(old.x); vv[1] += b2f(old.y); vv[2] += b2f(old.z); vv[3] += b2f(old.w);
      }
      if (RELU) {
#pragma unroll
        for (int r2 = 0; r2 < 4; r2++) vv[r2] = fmaxf(vv[r2], 0.f);
      }
      ushort4 st = { f2b(vv[0]), f2b(vv[1]), f2b(vv[2]), f2b(vv[3]) };
      *(ushort4*)dp = st;
    }
  }
}

// ---- V transpose: bufv[kn][pp][c] -> vt[ppc][c][kn]  (interior pp only) ----
__global__ __launch_bounds__(256) void vtrans_kernel(
    const unsigned short* __restrict__ v, unsigned short* __restrict__ vt) {
  int ppc = blockIdx.x;                       // 0..195
  int pp = (ppc / 14 + 1) * 16 + ppc % 14 + 1;
  int t = threadIdx.x;
  __shared__ unsigned short S[32 * 512];
#pragma unroll
  for (int i = 0; i < 8; i++) {
    int u = i * 256 + t;
    int kn = u >> 6, c8 = (u & 63) * 8;
    *(bhalf8*)&S[kn * 512 + c8] = *(const bhalf8*)(v + ((size_t)kn * 256 + pp) * 512 + c8);
  }
  __syncthreads();
#pragma unroll
  for (int half = 0; half < 2; half++) {
    int c = half * 256 + t;
    unsigned int col[16];
#pragma unroll
    for (int j = 0; j < 16; j++)
      col[j] = (unsigned int)S[(2 * j) * 512 + c] |
               ((unsigned int)S[(2 * j + 1) * 512 + c] << 16);
    unsigned short* dst = vt + ((size_t)ppc * 512 + c) * 32;
#pragma unroll
    for (int j = 0; j < 4; j++) {
      uint4 P = { col[j * 4], col[j * 4 + 1], col[j * 4 + 2], col[j * 4 + 3] };
      *(uint4*)(dst + j * 8) = P;
    }
  }
}

// ---------------------------------------------------------------------------
// Fused attention per pixel: QK^T (MFMA) -> in-register softmax -> PV (MFMA,
// C^T form via pre-transposed V) -> store vf + GroupNorm partials.
// ---------------------------------------------------------------------------
__global__ __launch_bounds__(64) void attfused_kernel(
    const unsigned short* __restrict__ q, const unsigned short* __restrict__ k,
    const unsigned short* __restrict__ vt, unsigned short* __restrict__ out,
    float* __restrict__ gnpart) {
  int pp = blockIdx.x;
  int h = pp >> 4, w = pp & 15;
  int l = threadIdx.x, l15 = l & 15, l4 = l >> 4;
  if (h < 1 || h > 14 || w < 1 || w > 14) {
    uint4 z = {0u, 0u, 0u, 0u};
#pragma unroll
    for (int qn = 0; qn < 32; qn++)
      *(uint4*)(out + ((size_t)qn * 256 + pp) * 512 + l * 8) = z;
    return;
  }
  int ppc = (h - 1) * 14 + (w - 1);

  // ---- QK^T: C[kn32][qn32], K=512 ----
  floatx4 sc[2][2] = {};
#pragma unroll
  for (int kb = 0; kb < 16; kb++) {
    bhalf8 A[2], B[2];
#pragma unroll
    for (int of = 0; of < 2; of++)
      A[of] = *(const bhalf8*)(k + ((size_t)(of * 16 + l15) * 256 + pp) * 512 + kb * 32 + l4 * 8);
#pragma unroll
    for (int pf = 0; pf < 2; pf++)
      B[pf] = *(const bhalf8*)(q + ((size_t)(pf * 16 + l15) * 256 + pp) * 512 + kb * 32 + l4 * 8);
#pragma unroll
    for (int of = 0; of < 2; of++)
#pragma unroll
      for (int pf = 0; pf < 2; pf++)
        sc[of][pf] = __builtin_amdgcn_mfma_f32_16x16x32_bf16(A[of], B[pf], sc[of][pf], 0, 0, 0);
  }

  // ---- softmax over kn (rows), per qn column; P -> LDS bf16 normalized ----
  __shared__ unsigned short p_lds[32 * 32];
  const float scale = 0.044194173824159216f;
#pragma unroll
  for (int pf = 0; pf < 2; pf++) {
    float v8[8];
    float m = -3.4e38f;
#pragma unroll
    for (int of = 0; of < 2; of++)
#pragma unroll
      for (int r = 0; r < 4; r++) {
        float x = sc[of][pf][r] * scale;
        v8[of * 4 + r] = x;
        m = fmaxf(m, x);
      }
    m = fmaxf(m, __shfl_xor(m, 16));
    m = fmaxf(m, __shfl_xor(m, 32));
    float s = 0.f;
#pragma unroll
    for (int i = 0; i < 8; i++) { v8[i] = __expf(v8[i] - m); s += v8[i]; }
    s += __shfl_xor(s, 16);
    s += __shfl_xor(s, 32);
    float inv = 1.f / s;
#pragma unroll
    for (int of = 0; of < 2; of++) {
      ushort4 pk = { f2b(v8[of * 4 + 0] * inv), f2b(v8[of * 4 + 1] * inv),
                     f2b(v8[of * 4 + 2] * inv), f2b(v8[of * 4 + 3] * inv) };
      *(ushort4*)&p_lds[(pf * 16 + l15) * 32 + of * 16 + l4 * 4] = pk;
    }
  }

  // ---- PV as C^T: C[c512][qn32] = VT[c][kn] @ P[qn][kn]^T, K=32 ----
  bhalf8 PB[2];
#pragma unroll
  for (int qf = 0; qf < 2; qf++)
    PB[qf] = *(const bhalf8*)&p_lds[(qf * 16 + l15) * 32 + l4 * 8];
  float gs[2] = {0.f, 0.f}, gss[2] = {0.f, 0.f};
  const unsigned short* vtb = vt + (size_t)ppc * 512 * 32;
#pragma unroll
  for (int chunk = 0; chunk < 4; chunk++) {
    bhalf8 VA[8];
#pragma unroll
    for (int co = 0; co < 8; co++)
      VA[co] = *(const bhalf8*)(vtb + (size_t)(chunk * 128 + co * 16 + l15) * 32 + l4 * 8);
#pragma unroll
    for (int co = 0; co < 8; co++)
#pragma unroll
      for (int qf = 0; qf < 2; qf++) {
        floatx4 pa = __builtin_amdgcn_mfma_f32_16x16x32_bf16(
            VA[co], PB[qf], (floatx4){0.f, 0.f, 0.f, 0.f}, 0, 0, 0);
        float x0 = pa[0], x1 = pa[1], x2 = pa[2], x3 = pa[3];
        gs[qf] += x0 + x1 + x2 + x3;
        gss[qf] += x0 * x0 + x1 * x1 + x2 * x2 + x3 * x3;
        ushort4 st = { f2b(x0), f2b(x1), f2b(x2), f2b(x3) };
        int qn = qf * 16 + l15;
        int c = chunk * 128 + co * 16 + l4 * 4;
        *(ushort4*)(out + ((size_t)qn * 256 + pp) * 512 + c) = st;
      }
  }
#pragma unroll
  for (int qf = 0; qf < 2; qf++) {
    gs[qf] += __shfl_xor(gs[qf], 16);  gs[qf] += __shfl_xor(gs[qf], 32);
    gss[qf] += __shfl_xor(gss[qf], 16); gss[qf] += __shfl_xor(gss[qf], 32);
  }
  if (l4 == 0) {
#pragma unroll
    for (int qf = 0; qf < 2; qf++) {
      int qn = qf * 16 + l15;
      gnpart[((size_t)ppc * 32 + qn) * 2]     = gs[qf];
      gnpart[((size_t)ppc * 32 + qn) * 2 + 1] = gss[qf];
    }
  }
}

// ---- GroupNorm: reduce partials + apply affine + relu (interior only) ----
__global__ __launch_bounds__(256) void gnapply3_kernel(
    unsigned short* __restrict__ x, const float* __restrict__ gnpart,
    const float* __restrict__ gamma, const float* __restrict__ beta) {
  int n = blockIdx.y, half = blockIdx.x, t = threadIdx.x;
  float s = 0.f, ss = 0.f;
  if (t < 196) {
    s  = gnpart[((size_t)t * 32 + n) * 2];
    ss = gnpart[((size_t)t * 32 + n) * 2 + 1];
  }
#pragma unroll
  for (int off = 32; off >= 1; off >>= 1) { s += __shfl_xor(s, off); ss += __shfl_xor(ss, off); }
  __shared__ float sm[8];
  int wv = t >> 6, ln = t & 63;
  if (ln == 0) { sm[wv] = s; sm[4 + wv] = ss; }
  __syncthreads();
  float S = sm[0] + sm[1] + sm[2] + sm[3];
  float SS = sm[4] + sm[5] + sm[6] + sm[7];
  const float M = 512.f * 196.f;
  float mu = S / M;
  float var = SS / M - mu * mu;
  float inv = rsqrtf(var + 1e-5f);
  int c2 = t * 2;
  unsigned short* xb = x + (size_t)n * ACT_N;
  float g0 = gamma[c2], g1 = gamma[c2 + 1];
  float be0 = beta[c2], be1 = beta[c2 + 1];
  for (int i = 0; i < 98; i++) {
    int ppc = half * 98 + i;
    int pp = (ppc / 14 + 1) * 16 + ppc % 14 + 1;
    unsigned int vv = *(unsigned int*)(xb + pp * 512 + c2);
    float a = (b2f((unsigned short)vv) - mu) * inv * g0 + be0;
    float b = (b2f((unsigned short)(vv >> 16)) - mu) * inv * g1 + be1;
    a = fmaxf(a, 0.f); b = fmaxf(b, 0.f);
    *(unsigned int*)(xb + pp * 512 + c2) =
        (unsigned int)f2b(a) | ((unsigned int)f2b(b) << 16);
  }
}

// ---- final: mean over interior 196 -> out[n][1024+c] (f32) ----
__global__ void fmean2_kernel(const unsigned short* __restrict__ x, float* __restrict__ out) {
  int n = blockIdx.x, t = threadIdx.x;
  const unsigned short* xb = x + (size_t)n * ACT_N;
  float s0 = 0.f, s1 = 0.f;
  for (int i = 0; i < 196; i++) {
    int pp = (i / 14 + 1) * 16 + (i % 14) + 1;
    unsigned int vv = *(const unsigned int*)(xb + pp * 512 + t * 2);
    s0 += b2f((unsigned short)vv);
    s1 += b2f((unsigned short)(vv >> 16));
  }
  out[(size_t)n * 1536 + 1024 + t * 2]     = s0 * (1.f / 196.f);
  out[(size_t)n * 1536 + 1024 + t * 2 + 1] = s1 * (1.f / 196.f);
}

extern "C" void kernel_launch(void* const* d_in, const int* in_sizes, int n_in,
                              void* d_out, int out_size, void* d_ws, size_t ws_size,
                              hipStream_t stream) {
  const float* x     = (const float*)d_in[0];
  const float* feat  = (const float*)d_in[1];
  const int*   rois  = (const int*)d_in[2];
  const float* w1    = (const float*)d_in[3];
  const float* w2    = (const float*)d_in[4];
  const float* wq    = (const float*)d_in[5];
  const float* wk    = (const float*)d_in[6];
  const float* wv    = (const float*)d_in[7];
  const float* wm    = (const float*)d_in[8];
  const float* gamma = (const float*)d_in[9];
  const float* beta  = (const float*)d_in[10];
  float* out = (float*)d_out;

  // ---- workspace layout ----
  // vt (6.42 MB) ALIASES [xp..W1g]: those are only used before the d-loop.
  float* wsf   = (float*)d_ws;
  float* xp    = wsf;                // 32768 f32
  float* bias1 = xp + 32768;         // 16384 f32
  float* stats = bias1 + 16384;      // 64 f32 (layout keep)
  float* attf  = stats + 64;         // 262144 f32 (layout keep)
  unsigned short* ub    = (unsigned short*)(attf + 262144);
  unsigned short* featT = ub;                    // 2097152 shorts
  unsigned short* W1g   = featT + 2097152;       // 524288 shorts
  unsigned short* Wg2   = W1g + 524288;          // 13*W3SZ shorts
  unsigned short* bufq  = Wg2 + 30670848;        // q/k/v contiguous
  unsigned short* bufk  = bufq + 4194304;
  unsigned short* bufv  = bufk + 4194304;
  unsigned short* bufx  = bufv + 4194304;
  unsigned short* vt    = (unsigned short*)d_ws; // 196*512*32 shorts
  float* gnpart = (float*)(bufx + 4194304);      // 196*32*2 f32

  // bufx border rows must be zero (only interior ever written by convs)
  hipMemsetAsync(bufx, 0, (size_t)4194304 * 2, stream);

  pool_max_kernel<<<8192, 256, 0, stream>>>(x, xp, out);
  bias1_kernel<<<4096, 256, 0, stream>>>(w1, xp, bias1);
  wprep3_kernel<<<dim3(16, 8, 13), 256, 0, stream>>>(w2, wq, wk, wv, wm, Wg2);
  w1prep_kernel<<<dim3(32, 8), 256, 0, stream>>>(w1, W1g);
  ftprep_kernel<<<dim3(4, 16, 8), 256, 0, stream>>>(feat, featT);

  // conv1: 1x1, K=1024, +bias1, relu, full 16x16 output -> bufq
  conv_mfma_kernel<1, 1024, 4, 4, 1, true, false, true, false>
      <<<dim3(32, 8), 256, 0, stream>>>(featT, rois, W1g, bias1, bufq);
  // conv2: valid 3x3 -> padded interior of bufx, relu
  conv_mfma_kernel<9, 512, 4, 4, 1, true, false, false, true>
      <<<dim3(32, 8), 256, 0, stream>>>(bufq, nullptr, Wg2, nullptr, bufx);

  for (int d = 0; d < 3; d++) {
    // q,k,v batched conv
    conv_mfma_kernel<9, 512, 4, 4, 1, false, false, false, true>
        <<<dim3(32, 24), 256, 0, stream>>>(bufx, nullptr,
            Wg2 + (size_t)(1 + 4 * d) * W3SZ, nullptr, bufq);
    vtrans_kernel<<<196, 256, 0, stream>>>(bufv, vt);
    attfused_kernel<<<256, 64, 0, stream>>>(bufq, bufk, vt, bufq, gnpart);
    gnapply3_kernel<<<dim3(2, 32), 256, 0, stream>>>(bufq, gnpart,
        gamma + d * 512, beta + d * 512);
    // wm conv + residual add into bufx
    conv_mfma_kernel<9, 512, 4, 4, 1, false, true, false, true>
        <<<dim3(32, 8), 256, 0, stream>>>(bufq, nullptr,
            Wg2 + (size_t)(4 + 4 * d) * W3SZ, nullptr, bufx);
  }

  fmean2_kernel<<<32, 256, 0, stream>>>(bufx, out);
}